// Round 4
// baseline (405.273 us; speedup 1.0000x reference)
//
#include <hip/hip_runtime.h>

// Atom_embedding_MP: B=4, N=100000, K=16, D=6, C_IN=13, 3 layers.
// Round-4:
//  - packed fp32 (v_pk_fma_f32) via float2 ext-vector fma: 13 output chans
//    as 6 pairs + 1 scalar -> ~halves inner-loop FMA issue count.
//  - lrelu sum factored: sum_k lrelu(x_k) = 0.6*sum_k x_k + 0.4*sum_k|x_k|;
//    sum_k x_k = 8*base_d + sum_j S_j*w_jd with S_j = sum_k feat (layer-
//    invariant, computed once) -> per-(d,k) only acc-FMA + |abs|-add.
//  - __launch_bounds__(256,3): ~168 VGPR budget so the 56 input floats stay
//    register-resident across layers (R2/R3: default budget 64 VGPR forced
//    per-layer reloads, VGPR_Count=60).
//  - 2 threads/point (8 neighbors each), pair-reduce via __shfl_xor(.,1).

typedef float f2 __attribute__((ext_vector_type(2)));

constexpr int DD  = 6;
constexpr int KK  = 16;
constexpr int CIN = 13;
constexpr float EPSV = 1e-5f;

__device__ __forceinline__ f2 pkfma(f2 a, f2 b, f2 c) {
    return __builtin_elementwise_fma(a, b, c);
}
__device__ __forceinline__ f2 splat(float x) { f2 r; r.x = x; r.y = x; return r; }

__global__ __launch_bounds__(256, 3) void atom_mp(
    const float* __restrict__ dist,   // [P, K]
    const float* __restrict__ at,     // [P, K, D]
    const float* __restrict__ W1,     // [3, CIN, CIN]
    const float* __restrict__ b1,     // [3, CIN]
    const float* __restrict__ W2,     // [3, CIN, D]
    const float* __restrict__ b2,     // [3, D]
    const float* __restrict__ gw,     // [3, D]
    const float* __restrict__ gb,     // [3, D]
    float* __restrict__ out,          // [P, D]
    int P)
{
    int t = blockIdx.x * blockDim.x + threadIdx.x;
    int p = t >> 1;      // point index
    int h = t & 1;       // neighbor half
    if (p >= P) return;

    // ---- register-resident input: 8 neighbors x 6 feats + 8 dists --------
    float a[8 * DD];
    float dq[8];
    const float4* ap4 = reinterpret_cast<const float4*>(
        at + (long)p * (KK * DD) + h * (8 * DD));
    #pragma unroll
    for (int i = 0; i < 12; ++i) {
        float4 q = ap4[i];
        a[4 * i + 0] = q.x; a[4 * i + 1] = q.y;
        a[4 * i + 2] = q.z; a[4 * i + 3] = q.w;
    }
    const float4* dp4 = reinterpret_cast<const float4*>(dist + (long)p * KK + h * 8);
    #pragma unroll
    for (int i = 0; i < 2; ++i) {
        float4 q = dp4[i];
        dq[4 * i + 0] = q.x; dq[4 * i + 1] = q.y;
        dq[4 * i + 2] = q.z; dq[4 * i + 3] = q.w;
    }

    // layer-invariant per-feature sums over this thread's 8 neighbors
    float S[7];
    #pragma unroll
    for (int j = 0; j < 6; ++j) {
        float s = a[j];
        #pragma unroll
        for (int k = 1; k < 8; ++k) s += a[6 * k + j];
        S[j] = s;
    }
    {
        float s = dq[0];
        #pragma unroll
        for (int k = 1; k < 8; ++k) s += dq[k];
        S[6] = s;
    }

    float pe[DD] = {1.f, 1.f, 1.f, 1.f, 1.f, 1.f};

    #pragma unroll 1
    for (int L = 0; L < 3; ++L) {
        const float* w1  = W1 + L * CIN * CIN;
        const float* w2  = W2 + L * CIN * DD;
        const float* bb1 = b1 + L * CIN;
        const float* bb2 = b2 + L * DD;
        const float* gwp = gw + L * DD;
        const float* gbp = gb + L * DD;

        // ---- base[d] = b1[d] + pe @ W1[0:6, d]  (6 pairs + 1 scalar) ----
        f2 base2[6];
        float base_s;
        #pragma unroll
        for (int dp = 0; dp < 6; ++dp) {
            f2 b = {bb1[2 * dp], bb1[2 * dp + 1]};
            #pragma unroll
            for (int c = 0; c < 6; ++c) {
                f2 w = {w1[c * CIN + 2 * dp], w1[c * CIN + 2 * dp + 1]};
                b = pkfma(splat(pe[c]), w, b);
            }
            base2[dp] = b;
        }
        base_s = bb1[12];
        #pragma unroll
        for (int c = 0; c < 6; ++c)
            base_s = fmaf(pe[c], w1[c * CIN + 12], base_s);

        // ---- linear part: lin[d] = 8*base_d + sum_j S_j * W1[6+j, d] ----
        f2 lin2[6];
        float lin_s;
        #pragma unroll
        for (int dp = 0; dp < 6; ++dp) {
            f2 l = base2[dp] * splat(8.f);
            #pragma unroll
            for (int j = 0; j < 7; ++j) {
                f2 w = {w1[(6 + j) * CIN + 2 * dp], w1[(6 + j) * CIN + 2 * dp + 1]};
                l = pkfma(splat(S[j]), w, l);
            }
            lin2[dp] = l;
        }
        lin_s = 8.f * base_s;
        #pragma unroll
        for (int j = 0; j < 7; ++j)
            lin_s = fmaf(S[j], w1[(6 + j) * CIN + 12], lin_s);

        // ---- abs part: habs[d] = sum_k |base_d + feat_k @ W1[6:,d]| ----
        float habs[CIN];
        #pragma unroll
        for (int d = 0; d < CIN; ++d) habs[d] = 0.f;

        #pragma unroll
        for (int k = 0; k < 8; ++k) {
            f2 acc2[6];
            float acc_s;
            {   // j = 0 folded into init
                float f0 = a[6 * k];
                f2 fv = splat(f0);
                #pragma unroll
                for (int dp = 0; dp < 6; ++dp) {
                    f2 w = {w1[6 * CIN + 2 * dp], w1[6 * CIN + 2 * dp + 1]};
                    acc2[dp] = pkfma(fv, w, base2[dp]);
                }
                acc_s = fmaf(f0, w1[6 * CIN + 12], base_s);
            }
            #pragma unroll
            for (int j = 1; j < 6; ++j) {
                float fj = a[6 * k + j];
                f2 fv = splat(fj);
                #pragma unroll
                for (int dp = 0; dp < 6; ++dp) {
                    f2 w = {w1[(6 + j) * CIN + 2 * dp], w1[(6 + j) * CIN + 2 * dp + 1]};
                    acc2[dp] = pkfma(fv, w, acc2[dp]);
                }
                acc_s = fmaf(fj, w1[(6 + j) * CIN + 12], acc_s);
            }
            {   // j = 6: distance channel
                float fj = dq[k];
                f2 fv = splat(fj);
                #pragma unroll
                for (int dp = 0; dp < 6; ++dp) {
                    f2 w = {w1[12 * CIN + 2 * dp], w1[12 * CIN + 2 * dp + 1]};
                    acc2[dp] = pkfma(fv, w, acc2[dp]);
                }
                acc_s = fmaf(fj, w1[12 * CIN + 12], acc_s);
            }
            // |.| accumulate (v_add_f32 with free abs modifier)
            #pragma unroll
            for (int dp = 0; dp < 6; ++dp) {
                habs[2 * dp]     += __builtin_fabsf(acc2[dp].x);
                habs[2 * dp + 1] += __builtin_fabsf(acc2[dp].y);
            }
            habs[12] += __builtin_fabsf(acc_s);
        }

        // ---- combine + pair-reduce: hsum[d] over all 16 neighbors ----
        float hsum[CIN];
        #pragma unroll
        for (int d = 0; d < CIN; ++d) {
            float lin_d = (d < 12) ? ((d & 1) ? lin2[d >> 1].y : lin2[d >> 1].x)
                                   : lin_s;
            float v = fmaf(0.6f, lin_d, 0.4f * habs[d]);
            hsum[d] = v + __shfl_xor(v, 1, 64);
        }

        // ---- msg = hsum @ W2 + 16*b2  (3 packed pairs over D=6) ----
        f2 msg2[3];
        #pragma unroll
        for (int dp = 0; dp < 3; ++dp) {
            f2 m = {16.f * bb2[2 * dp], 16.f * bb2[2 * dp + 1]};
            #pragma unroll
            for (int c = 0; c < CIN; ++c) {
                f2 w = {w2[c * DD + 2 * dp], w2[c * DD + 2 * dp + 1]};
                m = pkfma(splat(hsum[c]), w, m);
            }
            msg2[dp] = m;
        }
        float msg[DD] = {msg2[0].x, msg2[0].y, msg2[1].x, msg2[1].y,
                         msg2[2].x, msg2[2].y};

        // ---- GroupNorm(2x3) + affine + lrelu, residual ----
        #pragma unroll
        for (int g = 0; g < 2; ++g) {
            float m0 = msg[3 * g], m1 = msg[3 * g + 1], m2 = msg[3 * g + 2];
            float mu = (m0 + m1 + m2) * (1.f / 3.f);
            float d0 = m0 - mu, d1 = m1 - mu, d2 = m2 - mu;
            float var = (d0 * d0 + d1 * d1 + d2 * d2) * (1.f / 3.f);
            float rs = rsqrtf(var + EPSV);
            float dv[3] = {d0, d1, d2};
            #pragma unroll
            for (int c = 0; c < 3; ++c) {
                int ch = 3 * g + c;
                float xn = fmaf(dv[c] * rs, gwp[ch], gbp[ch]);
                pe[ch] = fmaf(0.6f, xn, pe[ch]);
                pe[ch] = fmaf(0.4f, __builtin_fabsf(xn), pe[ch]);
            }
        }
    }

    // both lanes hold identical pe; split the 6-float store across the pair
    float* op = out + (long)p * DD;
    if (h == 0) {
        *reinterpret_cast<float2*>(op)     = make_float2(pe[0], pe[1]);
        *reinterpret_cast<float2*>(op + 2) = make_float2(pe[2], pe[3]);
    } else {
        *reinterpret_cast<float2*>(op + 4) = make_float2(pe[4], pe[5]);
    }
}

extern "C" void kernel_launch(void* const* d_in, const int* in_sizes, int n_in,
                              void* d_out, int out_size, void* d_ws, size_t ws_size,
                              hipStream_t stream) {
    const float* dist = (const float*)d_in[0];
    const float* at   = (const float*)d_in[1];
    const float* W1   = (const float*)d_in[2];
    const float* b1   = (const float*)d_in[3];
    const float* W2   = (const float*)d_in[4];
    const float* b2   = (const float*)d_in[5];
    const float* gw   = (const float*)d_in[6];
    const float* gb   = (const float*)d_in[7];
    float* out = (float*)d_out;

    int P = in_sizes[0] / KK;   // dist is [P, K]
    long threads_total = 2L * P;
    int threads = 256;
    int blocks = (int)((threads_total + threads - 1) / threads);
    atom_mp<<<blocks, threads, 0, stream>>>(dist, at, W1, b1, W2, b2, gw, gb, out, P);
}

// Round 5
// 288.621 us; speedup vs baseline: 1.4042x; 1.4042x over previous
//
#include <hip/hip_runtime.h>

// Atom_embedding_MP: B=4, N=100000, K=16, D=6, C_IN=13, 3 layers.
// Round-5: LDS-staged inputs + packed fp32 math, small register footprint.
//  - R4 post-mortem: forcing 56-120 floats/thread to stay register-resident
//    caused scratch spills (WRITE_SIZE 9.4->255 MB, dur 240us). This round
//    stages each point's 112 input floats in LDS ONCE (one HBM/L3 read),
//    and every layer re-reads features from LDS (ds_read_b64, ~69 TB/s).
//    Per-layer live state ~65 VGPR -> no spill exposure at any occupancy.
//  - v_pk_fma_f32 via float2 ext-vector fma; weights are wave-uniform
//    s_loads (SGPR-pair operands, 1 SGPR/vector-instr -> no VGPR cost).
//  - lrelu(x) = max(x, 0.2x); 2 threads/point, pair-reduce via shfl_xor(1).
//  - LDS strides: at 98 dw/pt (8B-aligned rows, stride==2 mod 32 spreads
//    banks), dist 18 dw/pt. 59392 B/block -> 2 blocks/CU.

typedef float f2 __attribute__((ext_vector_type(2)));

constexpr int DD  = 6;
constexpr int KK  = 16;
constexpr int CIN = 13;
constexpr float EPSV = 1e-5f;

constexpr int ATS = 98;   // at LDS stride per point (dwords)
constexpr int DST = 18;   // dist LDS stride per point (dwords)

__device__ __forceinline__ f2 pkfma(f2 a, f2 b, f2 c) {
    return __builtin_elementwise_fma(a, b, c);
}
__device__ __forceinline__ f2 splat(float x) { f2 r; r.x = x; r.y = x; return r; }

__global__ __launch_bounds__(256) void atom_mp(
    const float* __restrict__ dist,   // [P, K]
    const float* __restrict__ at,     // [P, K, D]
    const float* __restrict__ W1,     // [3, CIN, CIN]
    const float* __restrict__ b1,     // [3, CIN]
    const float* __restrict__ W2,     // [3, CIN, D]
    const float* __restrict__ b2,     // [3, D]
    const float* __restrict__ gw,     // [3, D]
    const float* __restrict__ gb,     // [3, D]
    float* __restrict__ out,          // [P, D]
    int P)
{
    __shared__ float at_lds[128 * ATS];   // 50176 B
    __shared__ float d_lds [128 * DST];   //  9216 B

    int t = blockIdx.x * 256 + threadIdx.x;
    int p = t >> 1;
    if (p >= P) p = P - 1;          // safe clamp; grid divides exactly anyway
    int h  = t & 1;                 // neighbor half (0: k 0-7, 1: k 8-15)
    int lp = threadIdx.x >> 1;      // local point 0..127

    // ---- stage this thread's half-point into LDS (one global pass) ----
    {
        const float4* ga = reinterpret_cast<const float4*>(
            at + (long)p * (KK * DD) + h * 48);
        float* wa = at_lds + lp * ATS + h * 48;
        #pragma unroll
        for (int i = 0; i < 12; ++i) {
            float4 q = ga[i];
            *reinterpret_cast<float2*>(wa + 4 * i)     = make_float2(q.x, q.y);
            *reinterpret_cast<float2*>(wa + 4 * i + 2) = make_float2(q.z, q.w);
        }
        const float4* gd = reinterpret_cast<const float4*>(
            dist + (long)p * KK + h * 8);
        float* wd = d_lds + lp * DST + h * 8;
        #pragma unroll
        for (int i = 0; i < 2; ++i) {
            float4 q = gd[i];
            *reinterpret_cast<float2*>(wd + 4 * i)     = make_float2(q.x, q.y);
            *reinterpret_cast<float2*>(wd + 4 * i + 2) = make_float2(q.z, q.w);
        }
    }
    __syncthreads();

    const float* ra = at_lds + lp * ATS + h * 48;  // 8 rows of 6 floats
    const float* rd = d_lds  + lp * DST + h * 8;   // 8 dists

    float pe[DD] = {1.f, 1.f, 1.f, 1.f, 1.f, 1.f};

    #pragma unroll 1
    for (int L = 0; L < 3; ++L) {
        const float* w1  = W1 + L * CIN * CIN;
        const float* w2  = W2 + L * CIN * DD;
        const float* bb1 = b1 + L * CIN;
        const float* bb2 = b2 + L * DD;
        const float* gwp = gw + L * DD;
        const float* gbp = gb + L * DD;

        // ---- base[d] = b1[d] + pe @ W1[0:6, d]  (6 f2 pairs + 1 scalar) ----
        f2 base2[6];
        float base_s;
        #pragma unroll
        for (int dp = 0; dp < 6; ++dp) {
            f2 b; b.x = bb1[2 * dp]; b.y = bb1[2 * dp + 1];
            #pragma unroll
            for (int c = 0; c < 6; ++c) {
                f2 w; w.x = w1[c * CIN + 2 * dp]; w.y = w1[c * CIN + 2 * dp + 1];
                b = pkfma(splat(pe[c]), w, b);
            }
            base2[dp] = b;
        }
        base_s = bb1[12];
        #pragma unroll
        for (int c = 0; c < 6; ++c)
            base_s = fmaf(pe[c], w1[c * CIN + 12], base_s);

        // ---- neighbor loop: hs += lrelu(base + feat_k @ W1[6:13,:]) ----
        f2 hs2[6] = {};
        float hs_s = 0.f;

        #pragma unroll
        for (int k = 0; k < 8; ++k) {
            const float* row = ra + 6 * k;
            f2 f01 = *reinterpret_cast<const f2*>(row);      // ds_read_b64
            f2 f23 = *reinterpret_cast<const f2*>(row + 2);
            f2 f45 = *reinterpret_cast<const f2*>(row + 4);
            float f[7] = {f01.x, f01.y, f23.x, f23.y, f45.x, f45.y, rd[k]};

            f2 acc2[6];
            float acc_s;
            {   // j = 0 folded into init from base
                f2 fv = splat(f[0]);
                #pragma unroll
                for (int dp = 0; dp < 6; ++dp) {
                    f2 w; w.x = w1[6 * CIN + 2 * dp]; w.y = w1[6 * CIN + 2 * dp + 1];
                    acc2[dp] = pkfma(fv, w, base2[dp]);
                }
                acc_s = fmaf(f[0], w1[6 * CIN + 12], base_s);
            }
            #pragma unroll
            for (int j = 1; j < 7; ++j) {
                f2 fv = splat(f[j]);
                #pragma unroll
                for (int dp = 0; dp < 6; ++dp) {
                    f2 w; w.x = w1[(6 + j) * CIN + 2 * dp];
                    w.y = w1[(6 + j) * CIN + 2 * dp + 1];
                    acc2[dp] = pkfma(fv, w, acc2[dp]);
                }
                acc_s = fmaf(f[j], w1[(6 + j) * CIN + 12], acc_s);
            }
            // lrelu(x) = max(x, 0.2x); accumulate
            #pragma unroll
            for (int dp = 0; dp < 6; ++dp) {
                f2 v = acc2[dp];
                f2 s = v * splat(0.2f);          // v_pk_mul_f32
                v.x = fmaxf(v.x, s.x);
                v.y = fmaxf(v.y, s.y);
                hs2[dp] += v;                    // v_pk_add_f32
            }
            hs_s += fmaxf(acc_s, 0.2f * acc_s);
        }

        // ---- pair-reduce over the two half-threads of this point ----
        float hsum[CIN];
        #pragma unroll
        for (int dp = 0; dp < 6; ++dp) {
            hsum[2 * dp]     = hs2[dp].x + __shfl_xor(hs2[dp].x, 1, 64);
            hsum[2 * dp + 1] = hs2[dp].y + __shfl_xor(hs2[dp].y, 1, 64);
        }
        hsum[12] = hs_s + __shfl_xor(hs_s, 1, 64);

        // ---- msg = hsum @ W2 + 16*b2  (3 packed pairs over D=6) ----
        f2 msg2[3];
        #pragma unroll
        for (int dp = 0; dp < 3; ++dp) {
            f2 m; m.x = 16.f * bb2[2 * dp]; m.y = 16.f * bb2[2 * dp + 1];
            #pragma unroll
            for (int c = 0; c < CIN; ++c) {
                f2 w; w.x = w2[c * DD + 2 * dp]; w.y = w2[c * DD + 2 * dp + 1];
                m = pkfma(splat(hsum[c]), w, m);
            }
            msg2[dp] = m;
        }
        float msg[DD] = {msg2[0].x, msg2[0].y, msg2[1].x,
                         msg2[1].y, msg2[2].x, msg2[2].y};

        // ---- GroupNorm(2 groups of 3) + affine + lrelu, residual ----
        #pragma unroll
        for (int g = 0; g < 2; ++g) {
            float m0 = msg[3 * g], m1 = msg[3 * g + 1], m2 = msg[3 * g + 2];
            float mu = (m0 + m1 + m2) * (1.f / 3.f);
            float d0 = m0 - mu, d1 = m1 - mu, d2 = m2 - mu;
            float var = (d0 * d0 + d1 * d1 + d2 * d2) * (1.f / 3.f);
            float rs = rsqrtf(var + EPSV);
            float dv[3] = {d0, d1, d2};
            #pragma unroll
            for (int c = 0; c < 3; ++c) {
                int ch = 3 * g + c;
                float xn = fmaf(dv[c] * rs, gwp[ch], gbp[ch]);
                pe[ch] += fmaxf(xn, 0.2f * xn);
            }
        }
    }

    // both lanes of the pair hold identical pe; split the 6-float store
    float* op = out + (long)p * DD;
    if (h == 0) {
        *reinterpret_cast<float2*>(op)     = make_float2(pe[0], pe[1]);
        *reinterpret_cast<float2*>(op + 2) = make_float2(pe[2], pe[3]);
    } else {
        *reinterpret_cast<float2*>(op + 4) = make_float2(pe[4], pe[5]);
    }
}

extern "C" void kernel_launch(void* const* d_in, const int* in_sizes, int n_in,
                              void* d_out, int out_size, void* d_ws, size_t ws_size,
                              hipStream_t stream) {
    const float* dist = (const float*)d_in[0];
    const float* at   = (const float*)d_in[1];
    const float* W1   = (const float*)d_in[2];
    const float* b1   = (const float*)d_in[3];
    const float* W2   = (const float*)d_in[4];
    const float* b2   = (const float*)d_in[5];
    const float* gw   = (const float*)d_in[6];
    const float* gb   = (const float*)d_in[7];
    float* out = (float*)d_out;

    int P = in_sizes[0] / KK;          // dist is [P, K]
    long threads_total = 2L * P;
    int blocks = (int)((threads_total + 255) / 256);
    atom_mp<<<blocks, 256, 0, stream>>>(dist, at, W1, b1, W2, b2, gw, gb, out, P);
}